// Round 16
// baseline (1670.903 us; speedup 1.0000x reference)
//
#include <hip/hip_runtime.h>
#include <hip/hip_fp16.h>
#include <hip/hip_cooperative_groups.h>

namespace cg = cooperative_groups;

// Polarisation solver v16 = v12 (proven 324us: scans + 512T/STAGE4096/sbuck
// build + tight pack + 12B sorted recs) + 4B-histogram sort reads (v15)
// + 7 Jacobi passes fused into ONE cooperative kernel (grid.sync between).
// raw record (16B) = {dst|(localrow<<20), c1 f32, wx|wy f16x2, wz|g f16x2}.
// sorted record (12B) = {dst|(lr<<20), c1|wx f16x2, wy|wz f16x2}.

static constexpr float INV_B  = 1.0f / 0.52917721067f;            // 1/BOHR
static constexpr float INV_B3 = INV_B * INV_B * INV_B;            // 1/BOHR^3
static constexpr float DM = 0.39f;                                 // DAMP_MUTUAL
static constexpr float DF = 0.7f;                                  // DAMP_FIELD
static constexpr int   NITER = 7;
#define SCAN_B 1024
#define STAGE 4096
#define BUILD_T 512
#define CHUNK 8192
#define MAXBUCK 512

__device__ inline unsigned packh2(float a, float b) {
    return (unsigned)__half_as_ushort(__float2half_rn(a)) |
           ((unsigned)__half_as_ushort(__float2half_rn(b)) << 16);
}
__device__ inline float unph_lo(unsigned u) {
    return __half2float(__ushort_as_half((unsigned short)(u & 0xFFFFu)));
}
__device__ inline float unph_hi(unsigned u) {
    return __half2float(__ushort_as_half((unsigned short)(u >> 16)));
}

// ---- build: per-(block,bucket) histogram (tight counts, bucket-major) ----

__global__ void bhist_kernel(const int* __restrict__ esrc, int* __restrict__ h,
                             int E, int nbuck, int nblk, int chunk)
{
    __shared__ int cnt[MAXBUCK];
    int tid = threadIdx.x, blk = blockIdx.x;
    for (int b = tid; b < nbuck; b += blockDim.x) cnt[b] = 0;
    __syncthreads();
    int lo = blk * chunk, hi = min(E, lo + chunk);
    for (int i = lo + tid; i < hi; i += blockDim.x)
        atomicAdd(&cnt[esrc[i] >> 8], 1);
    __syncthreads();
    for (int b = tid; b < nbuck; b += blockDim.x)
        h[b * nblk + blk] = cnt[b];
}

// ---------------- 2-level exclusive scan (width 1024) ----------------

__global__ void scan1_kernel(const int* __restrict__ in, int* __restrict__ excl,
                             int* __restrict__ blocksum, int n)
{
    __shared__ int sh[SCAN_B];
    int tid = threadIdx.x;
    int i = blockIdx.x * SCAN_B + tid;
    int v = (i < n) ? in[i] : 0;
    sh[tid] = v;
    __syncthreads();
    for (int off = 1; off < SCAN_B; off <<= 1) {
        int t = (tid >= off) ? sh[tid - off] : 0;
        __syncthreads();
        sh[tid] += t;
        __syncthreads();
    }
    if (i < n) excl[i] = sh[tid] - v;
    if (tid == SCAN_B - 1) blocksum[blockIdx.x] = sh[tid];
}

__global__ void scan2_kernel(int* __restrict__ blocksum, int nb)
{
    __shared__ int sh[1024];
    int tid = threadIdx.x;
    int v = (tid < nb) ? blocksum[tid] : 0;
    sh[tid] = v;
    __syncthreads();
    for (int off = 1; off < 1024; off <<= 1) {
        int t = (tid >= off) ? sh[tid - off] : 0;
        __syncthreads();
        sh[tid] += t;
        __syncthreads();
    }
    if (tid < nb) blocksum[tid] = sh[tid] - v;
}

__global__ void scan3_kernel(int* __restrict__ excl, const int* __restrict__ blocksum, int n)
{
    int i = blockIdx.x * SCAN_B + threadIdx.x;
    if (i < n) excl[i] += blocksum[blockIdx.x];
}

// ---- bucket pointers (tight starts) ----

__global__ void bktptr_kernel(const int* __restrict__ hoff,
                              int* __restrict__ bktptr, int* __restrict__ rowptr,
                              int nbuck, int nblk, int N, int E)
{
    int b = blockIdx.x * blockDim.x + threadIdx.x;
    if (b < nbuck) bktptr[b] = hoff[b * nblk];
    if (b == nbuck) {
        bktptr[b] = E;
        if (rowptr) rowptr[N] = E;
    }
}

// ---- build: sequential reads, LDS bucket-sorted staging, coalesced dump ----
// matvec term: t = c1*mu_d - (w.mu_d)*w, w = sqrt(3*l5m*inv_r5)*vec_ij.
// E0 term: g*w with g = l3f*q_d*inv_r3 / sw.

__global__ __launch_bounds__(BUILD_T)
void build_kernel(const int* __restrict__ esrc, const int* __restrict__ edst,
                  const float* __restrict__ dist, const float* __restrict__ vec,
                  const float* __restrict__ pol, const float* __restrict__ chg,
                  const int* __restrict__ hoff,
                  uint4* __restrict__ recs, int E, int nbuck, int nblk, int chunk)
{
    __shared__ uint4 stg[STAGE];                    // 64 KB staged records
    __shared__ unsigned short sbuck[STAGE];         // 8 KB slot->bucket
    __shared__ int wcur[MAXBUCK];                   // running global cursor
    __shared__ int shist[MAXBUCK];                  // sub-batch counts
    __shared__ int sbase[MAXBUCK];                  // sub-batch exclusive scan
    __shared__ int scur[MAXBUCK];                   // sub-batch scatter cursor
    __shared__ int wsum[8];                         // wave totals for scan
    int tid = threadIdx.x, blk = blockIdx.x;
    int lane = tid & 63, wav = tid >> 6;
    int lo = blk * chunk, hi = min(E, lo + chunk), cnt = hi - lo;

    if (tid < nbuck) wcur[tid] = hoff[tid * nblk + blk];
    __syncthreads();

    int nsb = (cnt + STAGE - 1) / STAGE;
    for (int sb = 0; sb < nsb; ++sb) {
        int s0 = sb * STAGE, s1 = min(cnt, s0 + STAGE), scnt = s1 - s0;
        if (tid < nbuck) shist[tid] = 0;
        __syncthreads();
        for (int i = s0 + tid; i < s1; i += BUILD_T)
            atomicAdd(&shist[esrc[lo + i] >> 8], 1);
        __syncthreads();
        // wave-level exclusive scan over nbuck (<=512) entries
        int v = (tid < nbuck) ? shist[tid] : 0;
        int x = v;
        #pragma unroll
        for (int off = 1; off < 64; off <<= 1) {
            int t = __shfl_up(x, off);
            if (lane >= off) x += t;
        }
        if (lane == 63) wsum[wav] = x;
        __syncthreads();
        if (tid < 8) {
            int w = wsum[tid];
            #pragma unroll
            for (int off = 1; off < 8; off <<= 1) {
                int t = __shfl_up(w, off, 8);
                if (tid >= off) w += t;
            }
            wsum[tid] = w;                          // inclusive wave totals
        }
        __syncthreads();
        int base = (wav > 0) ? wsum[wav - 1] : 0;
        if (tid < nbuck) {
            int ex = x + base - v;
            sbase[tid] = ex;
            scur[tid]  = ex;
        }
        __syncthreads();
        // compute physics from SEQUENTIAL inputs; scatter record into LDS
        for (int i = s0 + tid; i < s1; i += BUILD_T) {
            int gi = lo + i;
            int s = esrc[gi], d = edst[gi];
            int b = s >> 8;
            float r  = dist[gi] * INV_B;
            float vx = vec[3*gi+0] * INV_B;
            float vy = vec[3*gi+1] * INV_B;
            float vz = vec[3*gi+2] * INV_B;
            float ps = pol[s] * INV_B3;
            float pd = pol[d] * INV_B3;
            float r2 = r * r;
            float r3 = r2 * r;
            float u  = r3 * rsqrtf(ps * pd);
            float em = __expf(-DM * u);
            float l3m = 1.0f - em;
            float l5m = 1.0f - (1.0f + DM * u) * em;
            float inv_r3 = 1.0f / r3;
            float inv_r5 = inv_r3 / r2;
            float c1 = l3m * inv_r3;
            float sw = sqrtf(3.0f * l5m * inv_r5);
            float ec = (1.0f - __expf(-DF * u)) * chg[d] * inv_r3;
            float g  = ec / sw;
            uint4 rc;
            rc.x = (unsigned)(d | ((s & 255) << 20));
            rc.y = __float_as_uint(c1);
            rc.z = packh2(sw * vx, sw * vy);
            rc.w = packh2(sw * vz, g);
            int sl = atomicAdd(&scur[b], 1);
            stg[sl]   = rc;
            sbuck[sl] = (unsigned short)b;
        }
        __syncthreads();
        // dump staged records: consecutive threads -> consecutive global slots
        for (int k = tid; k < scnt; k += BUILD_T) {
            int b = sbuck[k];
            recs[wcur[b] + (k - sbase[b])] = stg[k];
        }
        __syncthreads();
        if (tid < nbuck) wcur[tid] += shist[tid];
        __syncthreads();
    }
}

// ---- per-bucket counting sort -> tight row-CSR 12B records + fused E0/mu0 ----

__global__ void sort_kernel(const int* __restrict__ bktptr,
                            const uint4* __restrict__ recs_raw,
                            unsigned* __restrict__ srt,
                            int* __restrict__ rowptr, const float* __restrict__ pol,
                            float4* __restrict__ E0, float4* __restrict__ mu, int N)
{
    __shared__ int hist[256];
    __shared__ int cur[256];
    __shared__ float acc[256 * 3];
    __shared__ int wsum4[4];
    int tid = threadIdx.x, b = blockIdx.x;          // 512 threads
    int lane = tid & 63, wav = tid >> 6;
    int j0 = bktptr[b], j1 = bktptr[b + 1];
    if (tid < 256) hist[tid] = 0;
    for (int k = tid; k < 768; k += blockDim.x) acc[k] = 0.f;
    __syncthreads();
    const unsigned* recx = (const unsigned*)recs_raw;
    for (int j = j0 + tid; j < j1; j += blockDim.x)
        atomicAdd(&hist[recx[4 * (size_t)j] >> 20], 1);   // 4B load, not 16B
    __syncthreads();
    // wave-level exclusive scan of 256-entry hist (waves 0..3)
    int v = (tid < 256) ? hist[tid] : 0;
    int x = v;
    #pragma unroll
    for (int off = 1; off < 64; off <<= 1) {
        int t = __shfl_up(x, off);
        if (lane >= off) x += t;
    }
    if (lane == 63 && wav < 4) wsum4[wav] = x;
    __syncthreads();
    if (tid < 4) {
        int w = wsum4[tid];
        #pragma unroll
        for (int off = 1; off < 4; off <<= 1) {
            int t = __shfl_up(w, off, 4);
            if (tid >= off) w += t;
        }
        wsum4[tid] = w;
    }
    __syncthreads();
    if (tid < 256) {
        int base = (wav > 0) ? wsum4[wav - 1] : 0;
        int beg = j0 + x + base - v;                // tight: bucket base == j0
        cur[tid] = beg;
        int row = b * 256 + tid;
        if (row < N) rowptr[row] = beg;
    }
    __syncthreads();
    for (int j = j0 + tid; j < j1; j += blockDim.x) {
        uint4 rc = recs_raw[j];
        int lr = (int)(rc.x >> 20);
        int slot = atomicAdd(&cur[lr], 1);
        float c1 = __uint_as_float(rc.y);
        float wx = unph_lo(rc.z), wy = unph_hi(rc.z);
        float wz = unph_lo(rc.w), g  = unph_hi(rc.w);
        srt[3*slot+0] = rc.x;
        srt[3*slot+1] = packh2(c1, wx);
        srt[3*slot+2] = packh2(wy, wz);
        atomicAdd(&acc[lr*3+0], g * wx);            // fused E0 accumulation
        atomicAdd(&acc[lr*3+1], g * wy);
        atomicAdd(&acc[lr*3+2], g * wz);
    }
    __syncthreads();
    if (tid < 256) {
        int row = b * 256 + tid;
        if (row < N) {
            float ax = acc[tid*3], ay = acc[tid*3+1], az = acc[tid*3+2];
            E0[row] = make_float4(ax, ay, az, 0.f);
            float a = pol[row] * INV_B3;
            mu[row] = make_float4(a * ax, a * ay, a * az, 0.f);
        }
    }
}

// ---- iterate body (shared by coop and fallback) ----

__device__ inline void mvg_row(int row, int lane, const int* __restrict__ rowptr,
                               const unsigned* __restrict__ srt,
                               const float4* __restrict__ E0,
                               const float* __restrict__ pol,
                               const float4* __restrict__ mu_in,
                               float4* __restrict__ mu_out,
                               float* __restrict__ energy, int final_iter)
{
    int r0 = rowptr[row], r1 = rowptr[row + 1];
    float ax = 0.f, ay = 0.f, az = 0.f;
    for (int j = r0 + lane; j < r1; j += 16) {
        unsigned pk = srt[3*j+0];
        unsigned w0 = srt[3*j+1];
        unsigned w1 = srt[3*j+2];
        float4 m = mu_in[pk & 0xFFFFF];             // random 16B, L2-resident 1.6MB
        float c1 = unph_lo(w0);
        float wx = unph_hi(w0), wy = unph_lo(w1), wz = unph_hi(w1);
        float dot = wx * m.x + wy * m.y + wz * m.z;
        ax += c1 * m.x - dot * wx;
        ay += c1 * m.y - dot * wy;
        az += c1 * m.z - dot * wz;
    }
    for (int msk = 8; msk >= 1; msk >>= 1) {
        ax += __shfl_xor(ax, msk);
        ay += __shfl_xor(ay, msk);
        az += __shfl_xor(az, msk);
    }
    if (lane == 0) {
        float4 e0 = E0[row];
        float a = pol[row] * INV_B3;
        float mx = a * (e0.x - ax);
        float my = a * (e0.y - ay);
        float mz = a * (e0.z - az);
        mu_out[row] = make_float4(mx, my, mz, 0.f);
        if (final_iter)
            energy[row] = -0.5f * (mx * e0.x + my * e0.y + mz * e0.z);
    }
}

// ---- cooperative fused 7-pass Jacobi ----

__global__ void __launch_bounds__(256)
mvg_coop_kernel(const int* __restrict__ rowptr, const unsigned* __restrict__ srt,
                const float4* __restrict__ E0, const float* __restrict__ pol,
                float4* __restrict__ mu_a, float4* __restrict__ mu_b,
                float* __restrict__ energy, int N)
{
    cg::grid_group grid = cg::this_grid();
    int lane = threadIdx.x & 15;
    int rg0  = (int)((blockIdx.x * blockDim.x + threadIdx.x) >> 4);
    int rstride = (int)((gridDim.x * blockDim.x) >> 4);
    for (int it = 0; it < NITER; ++it) {
        const float4* min_  = (it & 1) ? mu_b : mu_a;
        float4*       mout_ = (it & 1) ? mu_a : mu_b;
        int fin = (it == NITER - 1);
        for (int row = rg0; row < N; row += rstride)
            mvg_row(row, lane, rowptr, srt, E0, pol, min_, mout_, energy, fin);
        if (it != NITER - 1) grid.sync();
    }
}

// ---- single-pass fallback (if cooperative sizing fails) ----

__global__ void mvg_kernel(const int* __restrict__ rowptr,
                           const unsigned* __restrict__ srt, const float4* __restrict__ E0,
                           const float* __restrict__ pol,
                           const float4* __restrict__ mu_in, float4* __restrict__ mu_out,
                           float* __restrict__ energy, int N, int final_iter)
{
    int lane = threadIdx.x & 15;
    int row  = (int)((blockIdx.x * blockDim.x + threadIdx.x) >> 4);
    if (row >= N) return;
    mvg_row(row, lane, rowptr, srt, E0, pol, mu_in, mu_out, energy, final_iter);
}

// ---------------- fallback (atomic path, tiny ws) ----------------

__global__ void fb_e0_kernel(const int* esrc, const int* edst, const float* dist,
                             const float* vec, const float* pol, const float* chg,
                             float4* E0, int E)
{
    int e = blockIdx.x * blockDim.x + threadIdx.x;
    if (e >= E) return;
    int s = esrc[e], d = edst[e];
    float r  = dist[e] * INV_B;
    float vx = vec[3*e+0]*INV_B, vy = vec[3*e+1]*INV_B, vz = vec[3*e+2]*INV_B;
    float r3 = r*r*r;
    float u  = r3 * rsqrtf(pol[s]*INV_B3 * pol[d]*INV_B3);
    float ec = (1.0f - __expf(-DF*u)) * chg[d] / r3;
    atomicAdd(&E0[s].x, ec*vx); atomicAdd(&E0[s].y, ec*vy); atomicAdd(&E0[s].z, ec*vz);
}

__global__ void fb_init_kernel(const float* pol, const float4* E0, float4* mu, float4* acc, int N)
{
    int i = blockIdx.x * blockDim.x + threadIdx.x;
    if (i >= N) return;
    float a = pol[i]*INV_B3; float4 e0 = E0[i];
    mu[i]  = make_float4(a*e0.x, a*e0.y, a*e0.z, 0.f);
    acc[i] = make_float4(0.f,0.f,0.f,0.f);
}

__global__ void fb_matvec_kernel(const int* esrc, const int* edst, const float* dist,
                                 const float* vec, const float* pol,
                                 const float4* mu, float4* acc, int E)
{
    int e = blockIdx.x * blockDim.x + threadIdx.x;
    if (e >= E) return;
    int s = esrc[e], d = edst[e];
    float r  = dist[e]*INV_B;
    float vx = vec[3*e+0]*INV_B, vy = vec[3*e+1]*INV_B, vz = vec[3*e+2]*INV_B;
    float r2 = r*r, r3 = r2*r;
    float u  = r3 * rsqrtf(pol[s]*INV_B3 * pol[d]*INV_B3);
    float em = __expf(-DM*u);
    float c1 = (1.0f - em) / r3;
    float c2 = 3.0f * (1.0f - (1.0f + DM*u)*em) / (r3*r2);
    float4 m = mu[d];
    float k = c2 * (vx*m.x + vy*m.y + vz*m.z);
    atomicAdd(&acc[s].x, c1*m.x - k*vx);
    atomicAdd(&acc[s].y, c1*m.y - k*vy);
    atomicAdd(&acc[s].z, c1*m.z - k*vz);
}

__global__ void fb_update_kernel(const float* pol, const float4* E0, float4* acc,
                                 float4* mu, float* energy, int N, int final_iter)
{
    int i = blockIdx.x * blockDim.x + threadIdx.x;
    if (i >= N) return;
    float a = pol[i]*INV_B3; float4 e0 = E0[i]; float4 ac = acc[i];
    float mx = a*(e0.x-ac.x), my = a*(e0.y-ac.y), mz = a*(e0.z-ac.z);
    mu[i]  = make_float4(mx,my,mz,0.f);
    acc[i] = make_float4(0.f,0.f,0.f,0.f);
    if (final_iter) energy[i] = -0.5f*(mx*e0.x + my*e0.y + mz*e0.z);
}

// ---------------- launch ----------------

static inline size_t align_up(size_t x, size_t a) { return (x + a - 1) & ~(a - 1); }

extern "C" void kernel_launch(void* const* d_in, const int* in_sizes, int n_in,
                              void* d_out, int out_size, void* d_ws, size_t ws_size,
                              hipStream_t stream)
{
    // inputs: species, edge_src, edge_dst, distances, vec, polarisability, charges
    const int*   esrc = (const int*)  d_in[1];
    const int*   edst = (const int*)  d_in[2];
    const float* dist = (const float*)d_in[3];
    const float* vec  = (const float*)d_in[4];
    const float* pol  = (const float*)d_in[5];
    const float* chg  = (const float*)d_in[6];
    const int E = in_sizes[1];
    const int N = in_sizes[5];
    float* out = (float*)d_out;

    const int nbuck = (N + 255) >> 8;                  // 391 for N=100k
    const int nblk  = (E + CHUNK - 1) / CHUNK;         // 392
    const int nScan = nbuck * nblk;
    const int g1    = (nScan + SCAN_B - 1) / SCAN_B;

    // workspace layout (~96 MB)
    char* ws = (char*)d_ws;
    size_t off = 0;
    auto carve = [&](size_t bytes) { size_t o = off; off = align_up(off + bytes, 256); return o; };
    size_t o_h      = carve((size_t)nScan * 4);
    size_t o_hoff   = carve((size_t)nScan * 4);
    size_t o_bsum   = carve(1024 * 4);
    size_t o_bkt    = carve((size_t)(nbuck + 1) * 4);
    size_t o_E0     = carve((size_t)N * 16);
    size_t o_mua    = carve((size_t)N * 16);
    size_t o_mub    = carve((size_t)N * 16);
    size_t o_rowptr = carve((size_t)(N + 1) * 4);
    size_t o_recs   = carve((size_t)E * 16);
    size_t o_srt    = carve((size_t)E * 12);
    size_t need = off;

    bool ok = (ws_size >= need) && (nbuck <= MAXBUCK) && (g1 <= 1024) &&
              (nbuck >= 1) && (N < (1 << 20));

    if (ok) {
        int*      h      = (int*)     (ws + o_h);
        int*      hoff   = (int*)     (ws + o_hoff);
        int*      bsum   = (int*)     (ws + o_bsum);
        int*      bktptr = (int*)     (ws + o_bkt);
        float4*   E0     = (float4*)  (ws + o_E0);
        float4*   mu_a   = (float4*)  (ws + o_mua);
        float4*   mu_b   = (float4*)  (ws + o_mub);
        int*      rowptr = (int*)     (ws + o_rowptr);
        uint4*    recs   = (uint4*)   (ws + o_recs);
        unsigned* srt    = (unsigned*)(ws + o_srt);

        bhist_kernel<<<nblk, BUILD_T, 0, stream>>>(esrc, h, E, nbuck, nblk, CHUNK);
        scan1_kernel<<<g1, SCAN_B, 0, stream>>>(h, hoff, bsum, nScan);
        scan2_kernel<<<1, 1024, 0, stream>>>(bsum, g1);
        scan3_kernel<<<g1, SCAN_B, 0, stream>>>(hoff, bsum, nScan);
        bktptr_kernel<<<(nbuck + 256) / 256, 256, 0, stream>>>(hoff, bktptr, rowptr,
                                                               nbuck, nblk, N, E);
        build_kernel<<<nblk, BUILD_T, 0, stream>>>(esrc, edst, dist, vec, pol, chg,
                                                   hoff, recs, E, nbuck, nblk, CHUNK);
        sort_kernel<<<nbuck, 512, 0, stream>>>(bktptr, recs, srt, rowptr,
                                               pol, E0, mu_a, N);

        // cooperative fused Jacobi (7 passes, grid.sync between)
        int blocksPerCU = 0, numCU = 0, dev = 0;
        hipGetDevice(&dev);
        hipDeviceGetAttribute(&numCU, hipDeviceAttributeMultiprocessorCount, dev);
        hipOccupancyMaxActiveBlocksPerMultiprocessor(
            &blocksPerCU, reinterpret_cast<const void*>(mvg_coop_kernel), 256, 0);
        long long wantBlocks = ((long long)N * 16 + 255) / 256;
        long long capBlocks  = (long long)blocksPerCU * numCU;
        int grid = (int)((capBlocks > 0) ? min(wantBlocks, capBlocks) : 0);

        if (grid > 0) {
            void* args[] = { (void*)&rowptr, (void*)&srt, (void*)&E0, (void*)&pol,
                             (void*)&mu_a, (void*)&mu_b, (void*)&out, (void*)&N };
            hipError_t err = hipLaunchCooperativeKernel(
                reinterpret_cast<const void*>(mvg_coop_kernel),
                dim3(grid), dim3(256), args, 0, stream);
            if (err == hipSuccess) return;
        }
        // fallback: 7 separate launches
        const int NG16 = (N + 15) / 16;
        float4* min_ = mu_a; float4* mout_ = mu_b;
        for (int it = 0; it < NITER; ++it) {
            mvg_kernel<<<NG16, 256, 0, stream>>>(rowptr, srt, E0, pol,
                                                 min_, mout_, out, N, it == NITER - 1);
            float4* t = min_; min_ = mout_; mout_ = t;
        }
    } else {
        // fallback: atomic scatter path (needs 48B/node)
        float4* E0  = (float4*)(ws);
        float4* mu  = (float4*)(ws + (size_t)N * 16);
        float4* acc = (float4*)(ws + (size_t)N * 32);
        const int EB = 256, NB = 256;
        const int EG = (E + EB - 1) / EB;
        const int NG = (N + NB - 1) / NB;
        hipMemsetAsync(E0, 0, (size_t)N * 16, stream);
        fb_e0_kernel<<<EG, EB, 0, stream>>>(esrc, edst, dist, vec, pol, chg, E0, E);
        fb_init_kernel<<<NG, NB, 0, stream>>>(pol, E0, mu, acc, N);
        for (int it = 0; it < NITER; ++it) {
            fb_matvec_kernel<<<EG, EB, 0, stream>>>(esrc, edst, dist, vec, pol, mu, acc, E);
            fb_update_kernel<<<NG, NB, 0, stream>>>(pol, E0, acc, mu, out, N, it == NITER - 1);
        }
    }
}

// Round 17
// 324.092 us; speedup vs baseline: 5.1556x; 5.1556x over previous
//
#include <hip/hip_runtime.h>
#include <hip/hip_fp16.h>

// Polarisation solver v17 = exact v12 (proven 324us optimum across 16 rounds).
// Tight (pad-free) bucket build with 4096-record LDS staging (long coalesced
// runs); per-bucket counting sort -> row-CSR 12B records + fused E0/mu0;
// atomic-free row-gather Jacobi iterations (7 separate launches — cooperative
// fusion REGRESSES 5x: grid.sync flushes per-XCD L2s, killing inter-pass reuse).
// raw record (16B) = {dst|(localrow<<20), c1 f32, wx|wy f16x2, wz|g f16x2}.
// sorted record (12B) = {dst|(lr<<20), c1|wx f16x2, wy|wz f16x2}.

static constexpr float INV_B  = 1.0f / 0.52917721067f;            // 1/BOHR
static constexpr float INV_B3 = INV_B * INV_B * INV_B;            // 1/BOHR^3
static constexpr float DM = 0.39f;                                 // DAMP_MUTUAL
static constexpr float DF = 0.7f;                                  // DAMP_FIELD
static constexpr int   NITER = 7;
#define SCAN_B 1024
#define STAGE 4096
#define BUILD_T 512
#define MAXBUCK 512

__device__ inline unsigned packh2(float a, float b) {
    return (unsigned)__half_as_ushort(__float2half_rn(a)) |
           ((unsigned)__half_as_ushort(__float2half_rn(b)) << 16);
}
__device__ inline float unph_lo(unsigned u) {
    return __half2float(__ushort_as_half((unsigned short)(u & 0xFFFFu)));
}
__device__ inline float unph_hi(unsigned u) {
    return __half2float(__ushort_as_half((unsigned short)(u >> 16)));
}

// ---- build: per-(block,bucket) histogram (tight counts, bucket-major) ----

__global__ void bhist_kernel(const int* __restrict__ esrc, int* __restrict__ h,
                             int E, int nbuck, int nblk, int chunk)
{
    __shared__ int cnt[MAXBUCK];
    int tid = threadIdx.x, blk = blockIdx.x;
    for (int b = tid; b < nbuck; b += blockDim.x) cnt[b] = 0;
    __syncthreads();
    int lo = blk * chunk, hi = min(E, lo + chunk);
    for (int i = lo + tid; i < hi; i += blockDim.x)
        atomicAdd(&cnt[esrc[i] >> 8], 1);
    __syncthreads();
    for (int b = tid; b < nbuck; b += blockDim.x)
        h[b * nblk + blk] = cnt[b];
}

// ---------------- 2-level exclusive scan (width 1024) ----------------

__global__ void scan1_kernel(const int* __restrict__ in, int* __restrict__ excl,
                             int* __restrict__ blocksum, int n)
{
    __shared__ int sh[SCAN_B];
    int tid = threadIdx.x;
    int i = blockIdx.x * SCAN_B + tid;
    int v = (i < n) ? in[i] : 0;
    sh[tid] = v;
    __syncthreads();
    for (int off = 1; off < SCAN_B; off <<= 1) {
        int t = (tid >= off) ? sh[tid - off] : 0;
        __syncthreads();
        sh[tid] += t;
        __syncthreads();
    }
    if (i < n) excl[i] = sh[tid] - v;
    if (tid == SCAN_B - 1) blocksum[blockIdx.x] = sh[tid];
}

__global__ void scan2_kernel(int* __restrict__ blocksum, int nb)
{
    __shared__ int sh[1024];
    int tid = threadIdx.x;
    int v = (tid < nb) ? blocksum[tid] : 0;
    sh[tid] = v;
    __syncthreads();
    for (int off = 1; off < 1024; off <<= 1) {
        int t = (tid >= off) ? sh[tid - off] : 0;
        __syncthreads();
        sh[tid] += t;
        __syncthreads();
    }
    if (tid < nb) blocksum[tid] = sh[tid] - v;
}

__global__ void scan3_kernel(int* __restrict__ excl, const int* __restrict__ blocksum, int n)
{
    int i = blockIdx.x * SCAN_B + threadIdx.x;
    if (i < n) excl[i] += blocksum[blockIdx.x];
}

// ---- bucket pointers (tight starts) ----

__global__ void bktptr_kernel(const int* __restrict__ hoff,
                              int* __restrict__ bktptr, int* __restrict__ rowptr,
                              int nbuck, int nblk, int N, int E)
{
    int b = blockIdx.x * blockDim.x + threadIdx.x;
    if (b < nbuck) bktptr[b] = hoff[b * nblk];
    if (b == nbuck) {
        bktptr[b] = E;
        if (rowptr) rowptr[N] = E;
    }
}

// ---- build: sequential reads, LDS bucket-sorted staging, coalesced dump ----
// matvec term: t = c1*mu_d - (w.mu_d)*w, w = sqrt(3*l5m*inv_r5)*vec_ij.
// E0 term: g*w with g = l3f*q_d*inv_r3 / sw.

__global__ __launch_bounds__(BUILD_T)
void build_kernel(const int* __restrict__ esrc, const int* __restrict__ edst,
                  const float* __restrict__ dist, const float* __restrict__ vec,
                  const float* __restrict__ pol, const float* __restrict__ chg,
                  const int* __restrict__ hoff,
                  uint4* __restrict__ recs, int E, int nbuck, int nblk, int chunk)
{
    __shared__ uint4 stg[STAGE];                    // 64 KB staged records
    __shared__ unsigned short sbuck[STAGE];         // 8 KB slot->bucket
    __shared__ int wcur[MAXBUCK];                   // running global cursor
    __shared__ int shist[MAXBUCK];                  // sub-batch counts
    __shared__ int sbase[MAXBUCK];                  // sub-batch exclusive scan
    __shared__ int scur[MAXBUCK];                   // sub-batch scatter cursor
    __shared__ int wsum[8];                         // wave totals for scan
    int tid = threadIdx.x, blk = blockIdx.x;
    int lane = tid & 63, wav = tid >> 6;
    int lo = blk * chunk, hi = min(E, lo + chunk), cnt = hi - lo;

    if (tid < nbuck) wcur[tid] = hoff[tid * nblk + blk];
    __syncthreads();

    int nsb = (cnt + STAGE - 1) / STAGE;
    for (int sb = 0; sb < nsb; ++sb) {
        int s0 = sb * STAGE, s1 = min(cnt, s0 + STAGE), scnt = s1 - s0;
        if (tid < nbuck) shist[tid] = 0;
        __syncthreads();
        for (int i = s0 + tid; i < s1; i += BUILD_T)
            atomicAdd(&shist[esrc[lo + i] >> 8], 1);
        __syncthreads();
        // wave-level exclusive scan over nbuck (<=512) entries
        int v = (tid < nbuck) ? shist[tid] : 0;
        int x = v;
        #pragma unroll
        for (int off = 1; off < 64; off <<= 1) {
            int t = __shfl_up(x, off);
            if (lane >= off) x += t;
        }
        if (lane == 63) wsum[wav] = x;
        __syncthreads();
        if (tid < 8) {
            int w = wsum[tid];
            #pragma unroll
            for (int off = 1; off < 8; off <<= 1) {
                int t = __shfl_up(w, off, 8);
                if (tid >= off) w += t;
            }
            wsum[tid] = w;                          // inclusive wave totals
        }
        __syncthreads();
        int base = (wav > 0) ? wsum[wav - 1] : 0;
        if (tid < nbuck) {
            int ex = x + base - v;
            sbase[tid] = ex;
            scur[tid]  = ex;
        }
        __syncthreads();
        // compute physics from SEQUENTIAL inputs; scatter record into LDS
        for (int i = s0 + tid; i < s1; i += BUILD_T) {
            int gi = lo + i;
            int s = esrc[gi], d = edst[gi];
            int b = s >> 8;
            float r  = dist[gi] * INV_B;
            float vx = vec[3*gi+0] * INV_B;
            float vy = vec[3*gi+1] * INV_B;
            float vz = vec[3*gi+2] * INV_B;
            float ps = pol[s] * INV_B3;
            float pd = pol[d] * INV_B3;
            float r2 = r * r;
            float r3 = r2 * r;
            float u  = r3 * rsqrtf(ps * pd);
            float em = __expf(-DM * u);
            float l3m = 1.0f - em;
            float l5m = 1.0f - (1.0f + DM * u) * em;
            float inv_r3 = 1.0f / r3;
            float inv_r5 = inv_r3 / r2;
            float c1 = l3m * inv_r3;
            float sw = sqrtf(3.0f * l5m * inv_r5);
            float ec = (1.0f - __expf(-DF * u)) * chg[d] * inv_r3;
            float g  = ec / sw;
            uint4 rc;
            rc.x = (unsigned)(d | ((s & 255) << 20));
            rc.y = __float_as_uint(c1);
            rc.z = packh2(sw * vx, sw * vy);
            rc.w = packh2(sw * vz, g);
            int sl = atomicAdd(&scur[b], 1);
            stg[sl]   = rc;
            sbuck[sl] = (unsigned short)b;
        }
        __syncthreads();
        // dump staged records: consecutive threads -> consecutive global slots
        for (int k = tid; k < scnt; k += BUILD_T) {
            int b = sbuck[k];
            recs[wcur[b] + (k - sbase[b])] = stg[k];
        }
        __syncthreads();
        if (tid < nbuck) wcur[tid] += shist[tid];
        __syncthreads();
    }
}

// ---- per-bucket counting sort -> tight row-CSR 12B records + fused E0/mu0 ----

__global__ void sort_kernel(const int* __restrict__ bktptr,
                            const uint4* __restrict__ recs_raw,
                            unsigned* __restrict__ srt,
                            int* __restrict__ rowptr, const float* __restrict__ pol,
                            float4* __restrict__ E0, float4* __restrict__ mu, int N)
{
    __shared__ int hist[256];
    __shared__ int cur[256];
    __shared__ float acc[256 * 3];
    __shared__ int wsum4[4];
    int tid = threadIdx.x, b = blockIdx.x;          // 512 threads
    int lane = tid & 63, wav = tid >> 6;
    int j0 = bktptr[b], j1 = bktptr[b + 1];
    if (tid < 256) hist[tid] = 0;
    for (int k = tid; k < 768; k += blockDim.x) acc[k] = 0.f;
    __syncthreads();
    for (int j = j0 + tid; j < j1; j += blockDim.x)
        atomicAdd(&hist[recs_raw[j].x >> 20], 1);
    __syncthreads();
    // wave-level exclusive scan of 256-entry hist (waves 0..3)
    int v = (tid < 256) ? hist[tid] : 0;
    int x = v;
    #pragma unroll
    for (int off = 1; off < 64; off <<= 1) {
        int t = __shfl_up(x, off);
        if (lane >= off) x += t;
    }
    if (lane == 63 && wav < 4) wsum4[wav] = x;
    __syncthreads();
    if (tid < 4) {
        int w = wsum4[tid];
        #pragma unroll
        for (int off = 1; off < 4; off <<= 1) {
            int t = __shfl_up(w, off, 4);
            if (tid >= off) w += t;
        }
        wsum4[tid] = w;
    }
    __syncthreads();
    if (tid < 256) {
        int base = (wav > 0) ? wsum4[wav - 1] : 0;
        int beg = j0 + x + base - v;                // tight: bucket base == j0
        cur[tid] = beg;
        int row = b * 256 + tid;
        if (row < N) rowptr[row] = beg;
    }
    __syncthreads();
    for (int j = j0 + tid; j < j1; j += blockDim.x) {
        uint4 rc = recs_raw[j];
        int lr = (int)(rc.x >> 20);
        int slot = atomicAdd(&cur[lr], 1);
        float c1 = __uint_as_float(rc.y);
        float wx = unph_lo(rc.z), wy = unph_hi(rc.z);
        float wz = unph_lo(rc.w), g  = unph_hi(rc.w);
        srt[3*slot+0] = rc.x;
        srt[3*slot+1] = packh2(c1, wx);
        srt[3*slot+2] = packh2(wy, wz);
        atomicAdd(&acc[lr*3+0], g * wx);            // fused E0 accumulation
        atomicAdd(&acc[lr*3+1], g * wy);
        atomicAdd(&acc[lr*3+2], g * wz);
    }
    __syncthreads();
    if (tid < 256) {
        int row = b * 256 + tid;
        if (row < N) {
            float ax = acc[tid*3], ay = acc[tid*3+1], az = acc[tid*3+2];
            E0[row] = make_float4(ax, ay, az, 0.f);
            float a = pol[row] * INV_B3;
            mu[row] = make_float4(a * ax, a * ay, a * az, 0.f);
        }
    }
}

// ---------------- iterate: row-CSR gather, 16 lanes/row, no atomics ----------------

__global__ void mvg_kernel(const int* __restrict__ rowptr,
                           const unsigned* __restrict__ srt, const float4* __restrict__ E0,
                           const float* __restrict__ pol,
                           const float4* __restrict__ mu_in, float4* __restrict__ mu_out,
                           float* __restrict__ energy, int N, int final_iter)
{
    int tid  = threadIdx.x;
    int lane = tid & 15;
    int row  = (blockIdx.x * blockDim.x + tid) >> 4;
    if (row >= N) return;
    int r0 = rowptr[row], r1 = rowptr[row + 1];
    float ax = 0.f, ay = 0.f, az = 0.f;
    for (int j = r0 + lane; j < r1; j += 16) {
        unsigned pk = srt[3*j+0];
        unsigned w0 = srt[3*j+1];
        unsigned w1 = srt[3*j+2];
        float4 m = mu_in[pk & 0xFFFFF];             // random 16B, L2-resident 1.6MB
        float c1 = unph_lo(w0);
        float wx = unph_hi(w0), wy = unph_lo(w1), wz = unph_hi(w1);
        float dot = wx * m.x + wy * m.y + wz * m.z;
        ax += c1 * m.x - dot * wx;
        ay += c1 * m.y - dot * wy;
        az += c1 * m.z - dot * wz;
    }
    for (int msk = 8; msk >= 1; msk >>= 1) {
        ax += __shfl_xor(ax, msk);
        ay += __shfl_xor(ay, msk);
        az += __shfl_xor(az, msk);
    }
    if (lane == 0) {
        float4 e0 = E0[row];
        float a = pol[row] * INV_B3;
        float mx = a * (e0.x - ax);
        float my = a * (e0.y - ay);
        float mz = a * (e0.z - az);
        mu_out[row] = make_float4(mx, my, mz, 0.f);
        if (final_iter)
            energy[row] = -0.5f * (mx * e0.x + my * e0.y + mz * e0.z);
    }
}

// ---------------- fallback (atomic path, tiny ws) ----------------

__global__ void fb_e0_kernel(const int* esrc, const int* edst, const float* dist,
                             const float* vec, const float* pol, const float* chg,
                             float4* E0, int E)
{
    int e = blockIdx.x * blockDim.x + threadIdx.x;
    if (e >= E) return;
    int s = esrc[e], d = edst[e];
    float r  = dist[e] * INV_B;
    float vx = vec[3*e+0]*INV_B, vy = vec[3*e+1]*INV_B, vz = vec[3*e+2]*INV_B;
    float r3 = r*r*r;
    float u  = r3 * rsqrtf(pol[s]*INV_B3 * pol[d]*INV_B3);
    float ec = (1.0f - __expf(-DF*u)) * chg[d] / r3;
    atomicAdd(&E0[s].x, ec*vx); atomicAdd(&E0[s].y, ec*vy); atomicAdd(&E0[s].z, ec*vz);
}

__global__ void fb_init_kernel(const float* pol, const float4* E0, float4* mu, float4* acc, int N)
{
    int i = blockIdx.x * blockDim.x + threadIdx.x;
    if (i >= N) return;
    float a = pol[i]*INV_B3; float4 e0 = E0[i];
    mu[i]  = make_float4(a*e0.x, a*e0.y, a*e0.z, 0.f);
    acc[i] = make_float4(0.f,0.f,0.f,0.f);
}

__global__ void fb_matvec_kernel(const int* esrc, const int* edst, const float* dist,
                                 const float* vec, const float* pol,
                                 const float4* mu, float4* acc, int E)
{
    int e = blockIdx.x * blockDim.x + threadIdx.x;
    if (e >= E) return;
    int s = esrc[e], d = edst[e];
    float r  = dist[e]*INV_B;
    float vx = vec[3*e+0]*INV_B, vy = vec[3*e+1]*INV_B, vz = vec[3*e+2]*INV_B;
    float r2 = r*r, r3 = r2*r;
    float u  = r3 * rsqrtf(pol[s]*INV_B3 * pol[d]*INV_B3);
    float em = __expf(-DM*u);
    float c1 = (1.0f - em) / r3;
    float c2 = 3.0f * (1.0f - (1.0f + DM*u)*em) / (r3*r2);
    float4 m = mu[d];
    float k = c2 * (vx*m.x + vy*m.y + vz*m.z);
    atomicAdd(&acc[s].x, c1*m.x - k*vx);
    atomicAdd(&acc[s].y, c1*m.y - k*vy);
    atomicAdd(&acc[s].z, c1*m.z - k*vz);
}

__global__ void fb_update_kernel(const float* pol, const float4* E0, float4* acc,
                                 float4* mu, float* energy, int N, int final_iter)
{
    int i = blockIdx.x * blockDim.x + threadIdx.x;
    if (i >= N) return;
    float a = pol[i]*INV_B3; float4 e0 = E0[i]; float4 ac = acc[i];
    float mx = a*(e0.x-ac.x), my = a*(e0.y-ac.y), mz = a*(e0.z-ac.z);
    mu[i]  = make_float4(mx,my,mz,0.f);
    acc[i] = make_float4(0.f,0.f,0.f,0.f);
    if (final_iter) energy[i] = -0.5f*(mx*e0.x + my*e0.y + mz*e0.z);
}

// ---------------- launch ----------------

static inline size_t align_up(size_t x, size_t a) { return (x + a - 1) & ~(a - 1); }

struct Layout {
    int chunk, nblk, nScan, g1;
    size_t o_h, o_hoff, o_bsum, o_bkt, o_E0, o_mua, o_mub, o_recs;
    size_t need_mid;
    size_t o_rowptr, o_srt;
    size_t need_sort;
};

static Layout make_layout(int E, int N, int nbuck, int chunk)
{
    Layout L;
    L.chunk = chunk;
    L.nblk  = (E + chunk - 1) / chunk;
    L.nScan = nbuck * L.nblk;
    L.g1    = (L.nScan + SCAN_B - 1) / SCAN_B;
    size_t off = 0;
    auto carve = [&](size_t bytes) { size_t o = off; off = align_up(off + bytes, 256); return o; };
    L.o_h      = carve((size_t)L.nScan * 4);
    L.o_hoff   = carve((size_t)L.nScan * 4);
    L.o_bsum   = carve(1024 * 4);
    L.o_bkt    = carve((size_t)(nbuck + 1) * 4);
    L.o_E0     = carve((size_t)N * 16);
    L.o_mua    = carve((size_t)N * 16);
    L.o_mub    = carve((size_t)N * 16);
    L.o_recs   = carve((size_t)E * 16);              // tight, no padding
    L.need_mid = off;
    L.o_rowptr = carve((size_t)(N + 1) * 4);
    L.o_srt    = carve((size_t)E * 12);
    L.need_sort = off;
    return L;
}

extern "C" void kernel_launch(void* const* d_in, const int* in_sizes, int n_in,
                              void* d_out, int out_size, void* d_ws, size_t ws_size,
                              hipStream_t stream)
{
    // inputs: species, edge_src, edge_dst, distances, vec, polarisability, charges
    const int*   esrc = (const int*)  d_in[1];
    const int*   edst = (const int*)  d_in[2];
    const float* dist = (const float*)d_in[3];
    const float* vec  = (const float*)d_in[4];
    const float* pol  = (const float*)d_in[5];
    const float* chg  = (const float*)d_in[6];
    const int E = in_sizes[1];
    const int N = in_sizes[5];
    float* out = (float*)d_out;

    const int nbuck = (N + 255) >> 8;                  // 391 for N=100k

    const int cand[3] = {8192, 16384, 32768};
    Layout L{}; bool ok_sort = false;
    for (int ci = 0; ci < 3; ++ci) {
        Layout t = make_layout(E, N, nbuck, cand[ci]);
        bool shp = (nbuck <= MAXBUCK) && (t.g1 <= 1024) && (nbuck >= 1) && (N < (1 << 20));
        if (shp && ws_size >= t.need_sort) { L = t; ok_sort = true; break; }
    }

    char* ws = (char*)d_ws;

    if (ok_sort) {
        int*      h      = (int*)     (ws + L.o_h);
        int*      hoff   = (int*)     (ws + L.o_hoff);
        int*      bsum   = (int*)     (ws + L.o_bsum);
        int*      bktptr = (int*)     (ws + L.o_bkt);
        float4*   E0     = (float4*)  (ws + L.o_E0);
        float4*   mu_a   = (float4*)  (ws + L.o_mua);
        float4*   mu_b   = (float4*)  (ws + L.o_mub);
        int*      rowptr = (int*)     (ws + L.o_rowptr);
        uint4*    recs   = (uint4*)   (ws + L.o_recs);
        unsigned* srt    = (unsigned*)(ws + L.o_srt);

        bhist_kernel<<<L.nblk, BUILD_T, 0, stream>>>(esrc, h, E, nbuck, L.nblk, L.chunk);
        scan1_kernel<<<L.g1, SCAN_B, 0, stream>>>(h, hoff, bsum, L.nScan);
        scan2_kernel<<<1, 1024, 0, stream>>>(bsum, L.g1);
        scan3_kernel<<<L.g1, SCAN_B, 0, stream>>>(hoff, bsum, L.nScan);
        bktptr_kernel<<<(nbuck + 256) / 256, 256, 0, stream>>>(hoff, bktptr, rowptr,
                                                               nbuck, L.nblk, N, E);
        build_kernel<<<L.nblk, BUILD_T, 0, stream>>>(esrc, edst, dist, vec, pol, chg,
                                                     hoff, recs, E, nbuck, L.nblk, L.chunk);
        sort_kernel<<<nbuck, 512, 0, stream>>>(bktptr, recs, srt, rowptr,
                                               pol, E0, mu_a, N);

        const int NG16 = (N + 15) / 16;
        float4* min_ = mu_a; float4* mout_ = mu_b;
        for (int it = 0; it < NITER; ++it) {
            mvg_kernel<<<NG16, 256, 0, stream>>>(rowptr, srt, E0, pol,
                                                 min_, mout_, out, N, it == NITER - 1);
            float4* t = min_; min_ = mout_; mout_ = t;
        }
    } else {
        // fallback: atomic scatter path (needs 48B/node)
        float4* E0  = (float4*)(ws);
        float4* mu  = (float4*)(ws + (size_t)N * 16);
        float4* acc = (float4*)(ws + (size_t)N * 32);
        const int EB = 256, NB = 256;
        const int EG = (E + EB - 1) / EB;
        const int NG = (N + NB - 1) / NB;
        hipMemsetAsync(E0, 0, (size_t)N * 16, stream);
        fb_e0_kernel<<<EG, EB, 0, stream>>>(esrc, edst, dist, vec, pol, chg, E0, E);
        fb_init_kernel<<<NG, NB, 0, stream>>>(pol, E0, mu, acc, N);
        for (int it = 0; it < NITER; ++it) {
            fb_matvec_kernel<<<EG, EB, 0, stream>>>(esrc, edst, dist, vec, pol, mu, acc, E);
            fb_update_kernel<<<NG, NB, 0, stream>>>(pol, E0, acc, mu, out, N, it == NITER - 1);
        }
    }
}

// Round 18
// 319.690 us; speedup vs baseline: 5.2266x; 1.0138x over previous
//
#include <hip/hip_runtime.h>
#include <hip/hip_fp16.h>

// Polarisation solver v18 = v12 with STAGE=CHUNK=8192: build's sub-batch loop
// collapses to a single pass (half the barriers, 2x coalesced run length,
// 152KB LDS, same 1-block/CU occupancy). Everything else bit-identical to the
// proven 324us v12: scans -> tight-pack bucket build -> per-bucket counting
// sort (12B recs + fused E0/mu0) -> 7 atomic-free row-gather Jacobi launches.
// raw record (16B) = {dst|(localrow<<20), c1 f32, wx|wy f16x2, wz|g f16x2}.
// sorted record (12B) = {dst|(lr<<20), c1|wx f16x2, wy|wz f16x2}.

static constexpr float INV_B  = 1.0f / 0.52917721067f;            // 1/BOHR
static constexpr float INV_B3 = INV_B * INV_B * INV_B;            // 1/BOHR^3
static constexpr float DM = 0.39f;                                 // DAMP_MUTUAL
static constexpr float DF = 0.7f;                                  // DAMP_FIELD
static constexpr int   NITER = 7;
#define SCAN_B 1024
#define STAGE 8192
#define BUILD_T 512
#define MAXBUCK 512

__device__ inline unsigned packh2(float a, float b) {
    return (unsigned)__half_as_ushort(__float2half_rn(a)) |
           ((unsigned)__half_as_ushort(__float2half_rn(b)) << 16);
}
__device__ inline float unph_lo(unsigned u) {
    return __half2float(__ushort_as_half((unsigned short)(u & 0xFFFFu)));
}
__device__ inline float unph_hi(unsigned u) {
    return __half2float(__ushort_as_half((unsigned short)(u >> 16)));
}

// ---- build: per-(block,bucket) histogram (tight counts, bucket-major) ----

__global__ void bhist_kernel(const int* __restrict__ esrc, int* __restrict__ h,
                             int E, int nbuck, int nblk, int chunk)
{
    __shared__ int cnt[MAXBUCK];
    int tid = threadIdx.x, blk = blockIdx.x;
    for (int b = tid; b < nbuck; b += blockDim.x) cnt[b] = 0;
    __syncthreads();
    int lo = blk * chunk, hi = min(E, lo + chunk);
    for (int i = lo + tid; i < hi; i += blockDim.x)
        atomicAdd(&cnt[esrc[i] >> 8], 1);
    __syncthreads();
    for (int b = tid; b < nbuck; b += blockDim.x)
        h[b * nblk + blk] = cnt[b];
}

// ---------------- 2-level exclusive scan (width 1024) ----------------

__global__ void scan1_kernel(const int* __restrict__ in, int* __restrict__ excl,
                             int* __restrict__ blocksum, int n)
{
    __shared__ int sh[SCAN_B];
    int tid = threadIdx.x;
    int i = blockIdx.x * SCAN_B + tid;
    int v = (i < n) ? in[i] : 0;
    sh[tid] = v;
    __syncthreads();
    for (int off = 1; off < SCAN_B; off <<= 1) {
        int t = (tid >= off) ? sh[tid - off] : 0;
        __syncthreads();
        sh[tid] += t;
        __syncthreads();
    }
    if (i < n) excl[i] = sh[tid] - v;
    if (tid == SCAN_B - 1) blocksum[blockIdx.x] = sh[tid];
}

__global__ void scan2_kernel(int* __restrict__ blocksum, int nb)
{
    __shared__ int sh[1024];
    int tid = threadIdx.x;
    int v = (tid < nb) ? blocksum[tid] : 0;
    sh[tid] = v;
    __syncthreads();
    for (int off = 1; off < 1024; off <<= 1) {
        int t = (tid >= off) ? sh[tid - off] : 0;
        __syncthreads();
        sh[tid] += t;
        __syncthreads();
    }
    if (tid < nb) blocksum[tid] = sh[tid] - v;
}

__global__ void scan3_kernel(int* __restrict__ excl, const int* __restrict__ blocksum, int n)
{
    int i = blockIdx.x * SCAN_B + threadIdx.x;
    if (i < n) excl[i] += blocksum[blockIdx.x];
}

// ---- bucket pointers (tight starts) ----

__global__ void bktptr_kernel(const int* __restrict__ hoff,
                              int* __restrict__ bktptr, int* __restrict__ rowptr,
                              int nbuck, int nblk, int N, int E)
{
    int b = blockIdx.x * blockDim.x + threadIdx.x;
    if (b < nbuck) bktptr[b] = hoff[b * nblk];
    if (b == nbuck) {
        bktptr[b] = E;
        if (rowptr) rowptr[N] = E;
    }
}

// ---- build: sequential reads, single full-chunk LDS bucket-sorted staging,
//      coalesced dump. matvec term: t = c1*mu_d - (w.mu_d)*w,
//      w = sqrt(3*l5m*inv_r5)*vec_ij. E0 term: g*w, g = l3f*q_d*inv_r3/sw. ----

__global__ __launch_bounds__(BUILD_T)
void build_kernel(const int* __restrict__ esrc, const int* __restrict__ edst,
                  const float* __restrict__ dist, const float* __restrict__ vec,
                  const float* __restrict__ pol, const float* __restrict__ chg,
                  const int* __restrict__ hoff,
                  uint4* __restrict__ recs, int E, int nbuck, int nblk, int chunk)
{
    __shared__ uint4 stg[STAGE];                    // 128 KB staged records
    __shared__ unsigned short sbuck[STAGE];         // 16 KB slot->bucket
    __shared__ int shist[MAXBUCK];                  // chunk counts
    __shared__ int sbase[MAXBUCK];                  // exclusive scan
    __shared__ int scur[MAXBUCK];                   // scatter cursor
    __shared__ int wbase[MAXBUCK];                  // global dest base
    __shared__ int wsum[8];                         // wave totals for scan
    int tid = threadIdx.x, blk = blockIdx.x;
    int lane = tid & 63, wav = tid >> 6;
    int lo = blk * chunk, hi = min(E, lo + chunk), cnt = hi - lo;

    if (tid < nbuck) {
        shist[tid] = 0;
        wbase[tid] = hoff[tid * nblk + blk];
    }
    __syncthreads();
    for (int i = tid; i < cnt; i += BUILD_T)
        atomicAdd(&shist[esrc[lo + i] >> 8], 1);
    __syncthreads();
    // wave-level exclusive scan over nbuck (<=512) entries
    int v = (tid < nbuck) ? shist[tid] : 0;
    int x = v;
    #pragma unroll
    for (int off = 1; off < 64; off <<= 1) {
        int t = __shfl_up(x, off);
        if (lane >= off) x += t;
    }
    if (lane == 63) wsum[wav] = x;
    __syncthreads();
    if (tid < 8) {
        int w = wsum[tid];
        #pragma unroll
        for (int off = 1; off < 8; off <<= 1) {
            int t = __shfl_up(w, off, 8);
            if (tid >= off) w += t;
        }
        wsum[tid] = w;                              // inclusive wave totals
    }
    __syncthreads();
    int base = (wav > 0) ? wsum[wav - 1] : 0;
    if (tid < nbuck) {
        int ex = x + base - v;
        sbase[tid] = ex;
        scur[tid]  = ex;
    }
    __syncthreads();
    // compute physics from SEQUENTIAL inputs; scatter record into LDS
    for (int i = tid; i < cnt; i += BUILD_T) {
        int gi = lo + i;
        int s = esrc[gi], d = edst[gi];
        int b = s >> 8;
        float r  = dist[gi] * INV_B;
        float vx = vec[3*gi+0] * INV_B;
        float vy = vec[3*gi+1] * INV_B;
        float vz = vec[3*gi+2] * INV_B;
        float ps = pol[s] * INV_B3;
        float pd = pol[d] * INV_B3;
        float r2 = r * r;
        float r3 = r2 * r;
        float u  = r3 * rsqrtf(ps * pd);
        float em = __expf(-DM * u);
        float l3m = 1.0f - em;
        float l5m = 1.0f - (1.0f + DM * u) * em;
        float inv_r3 = 1.0f / r3;
        float inv_r5 = inv_r3 / r2;
        float c1 = l3m * inv_r3;
        float sw = sqrtf(3.0f * l5m * inv_r5);
        float ec = (1.0f - __expf(-DF * u)) * chg[d] * inv_r3;
        float g  = ec / sw;
        uint4 rc;
        rc.x = (unsigned)(d | ((s & 255) << 20));
        rc.y = __float_as_uint(c1);
        rc.z = packh2(sw * vx, sw * vy);
        rc.w = packh2(sw * vz, g);
        int sl = atomicAdd(&scur[b], 1);
        stg[sl]   = rc;
        sbuck[sl] = (unsigned short)b;
    }
    __syncthreads();
    // dump staged records: consecutive threads -> consecutive global slots
    for (int k = tid; k < cnt; k += BUILD_T) {
        int b = sbuck[k];
        recs[wbase[b] + (k - sbase[b])] = stg[k];
    }
}

// ---- per-bucket counting sort -> tight row-CSR 12B records + fused E0/mu0 ----

__global__ void sort_kernel(const int* __restrict__ bktptr,
                            const uint4* __restrict__ recs_raw,
                            unsigned* __restrict__ srt,
                            int* __restrict__ rowptr, const float* __restrict__ pol,
                            float4* __restrict__ E0, float4* __restrict__ mu, int N)
{
    __shared__ int hist[256];
    __shared__ int cur[256];
    __shared__ float acc[256 * 3];
    __shared__ int wsum4[4];
    int tid = threadIdx.x, b = blockIdx.x;          // 512 threads
    int lane = tid & 63, wav = tid >> 6;
    int j0 = bktptr[b], j1 = bktptr[b + 1];
    if (tid < 256) hist[tid] = 0;
    for (int k = tid; k < 768; k += blockDim.x) acc[k] = 0.f;
    __syncthreads();
    for (int j = j0 + tid; j < j1; j += blockDim.x)
        atomicAdd(&hist[recs_raw[j].x >> 20], 1);
    __syncthreads();
    // wave-level exclusive scan of 256-entry hist (waves 0..3)
    int v = (tid < 256) ? hist[tid] : 0;
    int x = v;
    #pragma unroll
    for (int off = 1; off < 64; off <<= 1) {
        int t = __shfl_up(x, off);
        if (lane >= off) x += t;
    }
    if (lane == 63 && wav < 4) wsum4[wav] = x;
    __syncthreads();
    if (tid < 4) {
        int w = wsum4[tid];
        #pragma unroll
        for (int off = 1; off < 4; off <<= 1) {
            int t = __shfl_up(w, off, 4);
            if (tid >= off) w += t;
        }
        wsum4[tid] = w;
    }
    __syncthreads();
    if (tid < 256) {
        int base = (wav > 0) ? wsum4[wav - 1] : 0;
        int beg = j0 + x + base - v;                // tight: bucket base == j0
        cur[tid] = beg;
        int row = b * 256 + tid;
        if (row < N) rowptr[row] = beg;
    }
    __syncthreads();
    for (int j = j0 + tid; j < j1; j += blockDim.x) {
        uint4 rc = recs_raw[j];
        int lr = (int)(rc.x >> 20);
        int slot = atomicAdd(&cur[lr], 1);
        float c1 = __uint_as_float(rc.y);
        float wx = unph_lo(rc.z), wy = unph_hi(rc.z);
        float wz = unph_lo(rc.w), g  = unph_hi(rc.w);
        srt[3*slot+0] = rc.x;
        srt[3*slot+1] = packh2(c1, wx);
        srt[3*slot+2] = packh2(wy, wz);
        atomicAdd(&acc[lr*3+0], g * wx);            // fused E0 accumulation
        atomicAdd(&acc[lr*3+1], g * wy);
        atomicAdd(&acc[lr*3+2], g * wz);
    }
    __syncthreads();
    if (tid < 256) {
        int row = b * 256 + tid;
        if (row < N) {
            float ax = acc[tid*3], ay = acc[tid*3+1], az = acc[tid*3+2];
            E0[row] = make_float4(ax, ay, az, 0.f);
            float a = pol[row] * INV_B3;
            mu[row] = make_float4(a * ax, a * ay, a * az, 0.f);
        }
    }
}

// ---------------- iterate: row-CSR gather, 16 lanes/row, no atomics ----------------

__global__ void mvg_kernel(const int* __restrict__ rowptr,
                           const unsigned* __restrict__ srt, const float4* __restrict__ E0,
                           const float* __restrict__ pol,
                           const float4* __restrict__ mu_in, float4* __restrict__ mu_out,
                           float* __restrict__ energy, int N, int final_iter)
{
    int tid  = threadIdx.x;
    int lane = tid & 15;
    int row  = (blockIdx.x * blockDim.x + tid) >> 4;
    if (row >= N) return;
    int r0 = rowptr[row], r1 = rowptr[row + 1];
    float ax = 0.f, ay = 0.f, az = 0.f;
    for (int j = r0 + lane; j < r1; j += 16) {
        unsigned pk = srt[3*j+0];
        unsigned w0 = srt[3*j+1];
        unsigned w1 = srt[3*j+2];
        float4 m = mu_in[pk & 0xFFFFF];             // random 16B, L2-resident 1.6MB
        float c1 = unph_lo(w0);
        float wx = unph_hi(w0), wy = unph_lo(w1), wz = unph_hi(w1);
        float dot = wx * m.x + wy * m.y + wz * m.z;
        ax += c1 * m.x - dot * wx;
        ay += c1 * m.y - dot * wy;
        az += c1 * m.z - dot * wz;
    }
    for (int msk = 8; msk >= 1; msk >>= 1) {
        ax += __shfl_xor(ax, msk);
        ay += __shfl_xor(ay, msk);
        az += __shfl_xor(az, msk);
    }
    if (lane == 0) {
        float4 e0 = E0[row];
        float a = pol[row] * INV_B3;
        float mx = a * (e0.x - ax);
        float my = a * (e0.y - ay);
        float mz = a * (e0.z - az);
        mu_out[row] = make_float4(mx, my, mz, 0.f);
        if (final_iter)
            energy[row] = -0.5f * (mx * e0.x + my * e0.y + mz * e0.z);
    }
}

// ---------------- fallback (atomic path, tiny ws) ----------------

__global__ void fb_e0_kernel(const int* esrc, const int* edst, const float* dist,
                             const float* vec, const float* pol, const float* chg,
                             float4* E0, int E)
{
    int e = blockIdx.x * blockDim.x + threadIdx.x;
    if (e >= E) return;
    int s = esrc[e], d = edst[e];
    float r  = dist[e] * INV_B;
    float vx = vec[3*e+0]*INV_B, vy = vec[3*e+1]*INV_B, vz = vec[3*e+2]*INV_B;
    float r3 = r*r*r;
    float u  = r3 * rsqrtf(pol[s]*INV_B3 * pol[d]*INV_B3);
    float ec = (1.0f - __expf(-DF*u)) * chg[d] / r3;
    atomicAdd(&E0[s].x, ec*vx); atomicAdd(&E0[s].y, ec*vy); atomicAdd(&E0[s].z, ec*vz);
}

__global__ void fb_init_kernel(const float* pol, const float4* E0, float4* mu, float4* acc, int N)
{
    int i = blockIdx.x * blockDim.x + threadIdx.x;
    if (i >= N) return;
    float a = pol[i]*INV_B3; float4 e0 = E0[i];
    mu[i]  = make_float4(a*e0.x, a*e0.y, a*e0.z, 0.f);
    acc[i] = make_float4(0.f,0.f,0.f,0.f);
}

__global__ void fb_matvec_kernel(const int* esrc, const int* edst, const float* dist,
                                 const float* vec, const float* pol,
                                 const float4* mu, float4* acc, int E)
{
    int e = blockIdx.x * blockDim.x + threadIdx.x;
    if (e >= E) return;
    int s = esrc[e], d = edst[e];
    float r  = dist[e]*INV_B;
    float vx = vec[3*e+0]*INV_B, vy = vec[3*e+1]*INV_B, vz = vec[3*e+2]*INV_B;
    float r2 = r*r, r3 = r2*r;
    float u  = r3 * rsqrtf(pol[s]*INV_B3 * pol[d]*INV_B3);
    float em = __expf(-DM*u);
    float c1 = (1.0f - em) / r3;
    float c2 = 3.0f * (1.0f - (1.0f + DM*u)*em) / (r3*r2);
    float4 m = mu[d];
    float k = c2 * (vx*m.x + vy*m.y + vz*m.z);
    atomicAdd(&acc[s].x, c1*m.x - k*vx);
    atomicAdd(&acc[s].y, c1*m.y - k*vy);
    atomicAdd(&acc[s].z, c1*m.z - k*vz);
}

__global__ void fb_update_kernel(const float* pol, const float4* E0, float4* acc,
                                 float4* mu, float* energy, int N, int final_iter)
{
    int i = blockIdx.x * blockDim.x + threadIdx.x;
    if (i >= N) return;
    float a = pol[i]*INV_B3; float4 e0 = E0[i]; float4 ac = acc[i];
    float mx = a*(e0.x-ac.x), my = a*(e0.y-ac.y), mz = a*(e0.z-ac.z);
    mu[i]  = make_float4(mx,my,mz,0.f);
    acc[i] = make_float4(0.f,0.f,0.f,0.f);
    if (final_iter) energy[i] = -0.5f*(mx*e0.x + my*e0.y + mz*e0.z);
}

// ---------------- launch ----------------

static inline size_t align_up(size_t x, size_t a) { return (x + a - 1) & ~(a - 1); }

struct Layout {
    int chunk, nblk, nScan, g1;
    size_t o_h, o_hoff, o_bsum, o_bkt, o_E0, o_mua, o_mub, o_recs;
    size_t o_rowptr, o_srt;
    size_t need_sort;
};

static Layout make_layout(int E, int N, int nbuck, int chunk)
{
    Layout L;
    L.chunk = chunk;
    L.nblk  = (E + chunk - 1) / chunk;
    L.nScan = nbuck * L.nblk;
    L.g1    = (L.nScan + SCAN_B - 1) / SCAN_B;
    size_t off = 0;
    auto carve = [&](size_t bytes) { size_t o = off; off = align_up(off + bytes, 256); return o; };
    L.o_h      = carve((size_t)L.nScan * 4);
    L.o_hoff   = carve((size_t)L.nScan * 4);
    L.o_bsum   = carve(1024 * 4);
    L.o_bkt    = carve((size_t)(nbuck + 1) * 4);
    L.o_E0     = carve((size_t)N * 16);
    L.o_mua    = carve((size_t)N * 16);
    L.o_mub    = carve((size_t)N * 16);
    L.o_recs   = carve((size_t)E * 16);              // tight, no padding
    L.o_rowptr = carve((size_t)(N + 1) * 4);
    L.o_srt    = carve((size_t)E * 12);
    L.need_sort = off;
    return L;
}

extern "C" void kernel_launch(void* const* d_in, const int* in_sizes, int n_in,
                              void* d_out, int out_size, void* d_ws, size_t ws_size,
                              hipStream_t stream)
{
    // inputs: species, edge_src, edge_dst, distances, vec, polarisability, charges
    const int*   esrc = (const int*)  d_in[1];
    const int*   edst = (const int*)  d_in[2];
    const float* dist = (const float*)d_in[3];
    const float* vec  = (const float*)d_in[4];
    const float* pol  = (const float*)d_in[5];
    const float* chg  = (const float*)d_in[6];
    const int E = in_sizes[1];
    const int N = in_sizes[5];
    float* out = (float*)d_out;

    const int nbuck = (N + 255) >> 8;                  // 391 for N=100k

    // chunk must equal STAGE for the single-pass build
    Layout L = make_layout(E, N, nbuck, STAGE);
    bool ok_sort = (nbuck <= MAXBUCK) && (L.g1 <= 1024) && (nbuck >= 1) &&
                   (N < (1 << 20)) && (ws_size >= L.need_sort);

    char* ws = (char*)d_ws;

    if (ok_sort) {
        int*      h      = (int*)     (ws + L.o_h);
        int*      hoff   = (int*)     (ws + L.o_hoff);
        int*      bsum   = (int*)     (ws + L.o_bsum);
        int*      bktptr = (int*)     (ws + L.o_bkt);
        float4*   E0     = (float4*)  (ws + L.o_E0);
        float4*   mu_a   = (float4*)  (ws + L.o_mua);
        float4*   mu_b   = (float4*)  (ws + L.o_mub);
        int*      rowptr = (int*)     (ws + L.o_rowptr);
        uint4*    recs   = (uint4*)   (ws + L.o_recs);
        unsigned* srt    = (unsigned*)(ws + L.o_srt);

        bhist_kernel<<<L.nblk, BUILD_T, 0, stream>>>(esrc, h, E, nbuck, L.nblk, L.chunk);
        scan1_kernel<<<L.g1, SCAN_B, 0, stream>>>(h, hoff, bsum, L.nScan);
        scan2_kernel<<<1, 1024, 0, stream>>>(bsum, L.g1);
        scan3_kernel<<<L.g1, SCAN_B, 0, stream>>>(hoff, bsum, L.nScan);
        bktptr_kernel<<<(nbuck + 256) / 256, 256, 0, stream>>>(hoff, bktptr, rowptr,
                                                               nbuck, L.nblk, N, E);
        build_kernel<<<L.nblk, BUILD_T, 0, stream>>>(esrc, edst, dist, vec, pol, chg,
                                                     hoff, recs, E, nbuck, L.nblk, L.chunk);
        sort_kernel<<<nbuck, 512, 0, stream>>>(bktptr, recs, srt, rowptr,
                                               pol, E0, mu_a, N);

        const int NG16 = (N + 15) / 16;
        float4* min_ = mu_a; float4* mout_ = mu_b;
        for (int it = 0; it < NITER; ++it) {
            mvg_kernel<<<NG16, 256, 0, stream>>>(rowptr, srt, E0, pol,
                                                 min_, mout_, out, N, it == NITER - 1);
            float4* t = min_; min_ = mout_; mout_ = t;
        }
    } else {
        // fallback: atomic scatter path (needs 48B/node)
        float4* E0  = (float4*)(ws);
        float4* mu  = (float4*)(ws + (size_t)N * 16);
        float4* acc = (float4*)(ws + (size_t)N * 32);
        const int EB = 256, NB = 256;
        const int EG = (E + EB - 1) / EB;
        const int NG = (N + NB - 1) / NB;
        hipMemsetAsync(E0, 0, (size_t)N * 16, stream);
        fb_e0_kernel<<<EG, EB, 0, stream>>>(esrc, edst, dist, vec, pol, chg, E0, E);
        fb_init_kernel<<<NG, NB, 0, stream>>>(pol, E0, mu, acc, N);
        for (int it = 0; it < NITER; ++it) {
            fb_matvec_kernel<<<EG, EB, 0, stream>>>(esrc, edst, dist, vec, pol, mu, acc, E);
            fb_update_kernel<<<NG, NB, 0, stream>>>(pol, E0, acc, mu, out, N, it == NITER - 1);
        }
    }
}